// Round 1
// baseline (390.875 us; speedup 1.0000x reference)
//
#include <hip/hip_runtime.h>

#define L 32
#define W 262144
#define NN (L * W)

// Level 0: outs[i] = values[i] * w_term
__global__ void level0_kernel(const float* __restrict__ values,
                              const float* __restrict__ w_term,
                              float* __restrict__ outs) {
    int i = blockIdx.x * blockDim.x + threadIdx.x;
    outs[i] = values[i] * w_term[0];
}

// Level l (l>=1): gather 2 children from outs[0 : l*W), apply selected linear map.
__global__ void level_kernel(const int2* __restrict__ idx,   // this level's [W,2]
                             const int*  __restrict__ typ,   // this level's [W]
                             const float* __restrict__ w_plus,
                             const float* __restrict__ w_minus,
                             float* __restrict__ outs,
                             int base) {
    int i = blockIdx.x * blockDim.x + threadIdx.x;
    int2 c = idx[i];
    // two independent random gathers — issue both before use
    float x0 = outs[c.x];
    float x1 = outs[c.y];
    float wp0 = w_plus[0], wp1 = w_plus[1];
    float wm0 = w_minus[0], wm1 = w_minus[1];
    int t = typ[i];
    float o = (t == 1) ? (x0 * wp0 + x1 * wp1)
                       : (x0 * wm0 + x1 * wm1);
    outs[base + i] = o;
}

// Final scalar: out = outs[N-1] * w_final + b_final
__global__ void final_kernel(const float* __restrict__ outs,
                             const float* __restrict__ w_final,
                             const float* __restrict__ b_final,
                             float* __restrict__ out) {
    out[0] = outs[NN - 1] * w_final[0] + b_final[0];
}

extern "C" void kernel_launch(void* const* d_in, const int* in_sizes, int n_in,
                              void* d_out, int out_size, void* d_ws, size_t ws_size,
                              hipStream_t stream) {
    const float* values     = (const float*)d_in[0];
    const int*   child_idx  = (const int*)d_in[1];   // [L-1, W, 2]
    const int*   node_types = (const int*)d_in[2];   // [L-1, W]
    const float* w_term     = (const float*)d_in[3];
    const float* w_plus     = (const float*)d_in[4];
    const float* w_minus    = (const float*)d_in[5];
    const float* w_final    = (const float*)d_in[6];
    const float* b_final    = (const float*)d_in[7];

    float* outs = (float*)d_ws;   // N floats = 33.5 MB prefix array
    float* out  = (float*)d_out;

    dim3 block(256);
    dim3 grid(W / 256);           // 1024 blocks

    level0_kernel<<<grid, block, 0, stream>>>(values, w_term, outs);
    for (int l = 1; l < L; ++l) {
        level_kernel<<<grid, block, 0, stream>>>(
            (const int2*)(child_idx + (size_t)(l - 1) * W * 2),
            node_types + (size_t)(l - 1) * W,
            w_plus, w_minus, outs, l * W);
    }
    final_kernel<<<1, 1, 0, stream>>>(outs, w_final, b_final, out);
}